// Round 2
// baseline (463.858 us; speedup 1.0000x reference)
//
#include <hip/hip_runtime.h>

typedef unsigned short u16;
typedef unsigned int   u32;
typedef __attribute__((ext_vector_type(8))) short  short8;   // 8 x bf16
typedef __attribute__((ext_vector_type(4))) float  floatx4;

#define NEGF (-1000000000.0f)

__device__ __forceinline__ u16 f2bf(float x) {            // f32 -> bf16 RNE
  u32 u = __builtin_bit_cast(u32, x);
  u += 0x7fffu + ((u >> 16) & 1u);
  return (u16)(u >> 16);
}

// LDS swizzles (ushort index space; byte-XOR = 2x these)
__device__ __forceinline__ int swzK(int row, int col) {   // K[64][128]
  return row * 128 + (col ^ ((row & 7) << 3));
}
__device__ __forceinline__ int swzV(int d, int kv) {      // Vt[128][64]
  return d * 64 + (kv ^ (((d & 7) ^ ((d >> 2) & 7)) << 3));
}
__device__ __forceinline__ int swzP(int row, int col) {   // P[16][64]
  return row * 64 + (col ^ ((row & 7) << 3));
}

constexpr int Hh = 16, Ss = 2048, Dd = 128;
constexpr int QBLK = 64, KVBLK = 64;
constexpr int NT = Ss / KVBLK;   // 32 kv tiles

__global__ __launch_bounds__(256) void attn_fwd(
    const float* __restrict__ Q, const float* __restrict__ K,
    const float* __restrict__ V, const int* __restrict__ MSK,
    float* __restrict__ O)
{
  __shared__ u16 Kl[KVBLK * Dd];        // 16 KB, swizzled row-major
  __shared__ u16 Vt[Dd * KVBLK];        // 16 KB, transposed + swizzled
  __shared__ u16 Pl[4][16 * KVBLK];     // 8 KB, per-wave P tile
  __shared__ int sAff;                  // block needs future tiles?

  const int tid = threadIdx.x, lane = tid & 63, wid = tid >> 6;
  const int l15 = lane & 15, lg = lane >> 4;
  const int qt = blockIdx.x, bh = blockIdx.y, b = bh >> 4;   // H = 16
  const int qbase = qt * QBLK;
  const float scale = 0.08838834764831845f;                  // 1/sqrt(128)

  // ---- Q fragments: A-layout row = lane&15, k = (lane>>4)*8 + i ----
  const int qrowA = qbase + wid * 16 + l15;
  const float* qg = Q + ((size_t)bh * Ss + qrowA) * Dd + lg * 8;
  short8 qf[4];
  #pragma unroll
  for (int kc = 0; kc < 4; ++kc) {
    float4 x0 = *(const float4*)(qg + kc * 32);
    float4 x1 = *(const float4*)(qg + kc * 32 + 4);
    union { short8 v; u16 s[8]; } u;
    u.s[0] = f2bf(x0.x * scale); u.s[1] = f2bf(x0.y * scale);
    u.s[2] = f2bf(x0.z * scale); u.s[3] = f2bf(x0.w * scale);
    u.s[4] = f2bf(x1.x * scale); u.s[5] = f2bf(x1.y * scale);
    u.s[6] = f2bf(x1.z * scale); u.s[7] = f2bf(x1.w * scale);
    qf[kc] = u.v;
  }

  float m_run[4], l_run[4];
  floatx4 oacc[8];
  const floatx4 vzero = {0.f, 0.f, 0.f, 0.f};
  #pragma unroll
  for (int r = 0; r < 4; ++r) { m_run[r] = -3.0e38f; l_run[r] = 0.0f; }
  #pragma unroll
  for (int dt = 0; dt < 8; ++dt) oacc[dt] = vzero;

  const int qi0 = qbase + wid * 16 + lg * 4;   // C/D row base for this lane

  // Causal tiles t<=qt always.  Tiles t>qt matter ONLY for rows whose whole
  // visible prefix is padding-masked: there the reference's additive -1e9
  // puts future unmasked cols at the SAME -1e9 level as the visible ones,
  // so they share softmax weight.  Detect per-block after the diagonal tile
  // (running max ~ -1e9) and only then continue into future tiles; for
  // normal rows those tiles contribute alpha=1, p=0 (exact no-op).
  for (int t = 0; t < NT; ++t) {
    if (t > qt && !sAff) break;
    const int kvbase = t * KVBLK;
    const float* kg = K + ((size_t)bh * Ss + kvbase) * Dd;
    const float* vg = V + ((size_t)bh * Ss + kvbase) * Dd;

    // ---- stage K (swizzled) and V (transposed+swizzled), f32 -> bf16 ----
    #pragma unroll
    for (int it = 0; it < 8; ++it) {
      int e = (tid + it * 256) * 4;            // flat f32 element
      int r0 = e >> 7, c0 = e & 127;           // r0 = kv row, c0 = d col
      float4 x = *(const float4*)(kg + e);
      uint2 hk;
      hk.x = (u32)f2bf(x.x) | ((u32)f2bf(x.y) << 16);
      hk.y = (u32)f2bf(x.z) | ((u32)f2bf(x.w) << 16);
      *(uint2*)&Kl[swzK(r0, c0)] = hk;
      float4 y = *(const float4*)(vg + e);
      u16 hv[4] = { f2bf(y.x), f2bf(y.y), f2bf(y.z), f2bf(y.w) };
      #pragma unroll
      for (int j = 0; j < 4; ++j) Vt[swzV(c0 + j, r0)] = hv[j];
    }
    __syncthreads();

    // ---- padding mask adds (fp32, additive like reference) ----
    float madd[4];
    #pragma unroll
    for (int kt = 0; kt < 4; ++kt)
      madd[kt] = MSK[b * Ss + kvbase + kt * 16 + l15] ? 0.0f : NEGF;

    // ---- S = (Q*scale) . K^T via 16 MFMAs ----
    floatx4 sacc[4];
    #pragma unroll
    for (int kt = 0; kt < 4; ++kt) sacc[kt] = vzero;
    #pragma unroll
    for (int kt = 0; kt < 4; ++kt) {
      const int krow = kt * 16 + l15;
      #pragma unroll
      for (int kc = 0; kc < 4; ++kc) {
        short8 kf = *(const short8*)&Kl[swzK(krow, kc * 32 + lg * 8)];
        sacc[kt] = __builtin_amdgcn_mfma_f32_16x16x32_bf16(qf[kc], kf, sacc[kt], 0, 0, 0);
      }
    }

    // ---- masks + online softmax (row = qi0+r, col = kvbase+kt*16+l15) ----
    float mnew[4];
    #pragma unroll
    for (int r = 0; r < 4; ++r) mnew[r] = m_run[r];
    #pragma unroll
    for (int kt = 0; kt < 4; ++kt) {
      const int kvj = kvbase + kt * 16 + l15;
      #pragma unroll
      for (int r = 0; r < 4; ++r) {
        float s = sacc[kt][r] + madd[kt];      // padding first (like ref)
        if (kvj > qi0 + r) s += NEGF;          // then causal (like ref)
        sacc[kt][r] = s;
        mnew[r] = fmaxf(mnew[r], s);
      }
    }
    #pragma unroll
    for (int off = 1; off < 16; off <<= 1) {
      #pragma unroll
      for (int r = 0; r < 4; ++r)
        mnew[r] = fmaxf(mnew[r], __shfl_xor(mnew[r], off, 64));
    }
    float alpha[4], psum[4];
    #pragma unroll
    for (int r = 0; r < 4; ++r) {
      alpha[r] = __expf(m_run[r] - mnew[r]);
      m_run[r] = mnew[r];
      psum[r] = 0.f;
    }
    #pragma unroll
    for (int kt = 0; kt < 4; ++kt) {
      #pragma unroll
      for (int r = 0; r < 4; ++r) {
        float p = __expf(sacc[kt][r] - mnew[r]);
        psum[r] += p;
        Pl[wid][swzP(lg * 4 + r, kt * 16 + l15)] = f2bf(p);
      }
    }
    #pragma unroll
    for (int off = 1; off < 16; off <<= 1) {
      #pragma unroll
      for (int r = 0; r < 4; ++r)
        psum[r] += __shfl_xor(psum[r], off, 64);
    }
    #pragma unroll
    for (int r = 0; r < 4; ++r) l_run[r] = l_run[r] * alpha[r] + psum[r];
    #pragma unroll
    for (int dt = 0; dt < 8; ++dt) {
      #pragma unroll
      for (int r = 0; r < 4; ++r) oacc[dt][r] *= alpha[r];
    }

    // ---- O += P . V via 16 MFMAs (P from per-wave LDS, V transposed) ----
    #pragma unroll
    for (int kc = 0; kc < 2; ++kc) {
      short8 pf = *(const short8*)&Pl[wid][swzP(l15, kc * 32 + lg * 8)];
      #pragma unroll
      for (int dt = 0; dt < 8; ++dt) {
        short8 vf = *(const short8*)&Vt[swzV(dt * 16 + l15, kc * 32 + lg * 8)];
        oacc[dt] = __builtin_amdgcn_mfma_f32_16x16x32_bf16(pf, vf, oacc[dt], 0, 0, 0);
      }
    }
    __syncthreads();

    // ---- after the diagonal tile: do any rows need the future tiles? ----
    if (t == qt) {
      if (tid == 0) sAff = 0;
      __syncthreads();
      bool aff = (m_run[0] < -5.0e8f) || (m_run[1] < -5.0e8f) ||
                 (m_run[2] < -5.0e8f) || (m_run[3] < -5.0e8f);
      if (aff) sAff = 1;                 // benign race: same value
      __syncthreads();
    }
  }

  // ---- epilogue: O /= l ----
  #pragma unroll
  for (int r = 0; r < 4; ++r) {
    float inv = 1.0f / l_run[r];
    float* op = O + ((size_t)bh * Ss + qi0 + r) * Dd + l15;
    #pragma unroll
    for (int dt = 0; dt < 8; ++dt) op[dt * 16] = oacc[dt][r] * inv;
  }
}

extern "C" void kernel_launch(void* const* d_in, const int* in_sizes, int n_in,
                              void* d_out, int out_size, void* d_ws, size_t ws_size,
                              hipStream_t stream) {
  const float* q = (const float*)d_in[0];
  const float* k = (const float*)d_in[1];
  const float* v = (const float*)d_in[2];
  const int* mask = (const int*)d_in[3];
  float* out = (float*)d_out;
  dim3 grid(Ss / QBLK, 4 * Hh);   // 32 q-tiles x 64 (b,h)
  attn_fwd<<<grid, 256, 0, stream>>>(q, k, v, mask, out);
}

// Round 3
// 316.743 us; speedup vs baseline: 1.4645x; 1.4645x over previous
//
#include <hip/hip_runtime.h>

typedef unsigned short u16;
typedef unsigned int   u32;
typedef __attribute__((ext_vector_type(8))) short  short8;   // 8 x bf16
typedef __attribute__((ext_vector_type(4))) float  floatx4;

#define CNEG  (-1.4426950408889634e9f)   // -1e9 * log2(e)  (exp2 domain)
#define QSCL  (0.12753129020334545f)     // (1/sqrt(128)) * log2(e)
#define NEGF  (-1000000000.0f)           // fallback kernel (exp domain)

__device__ __forceinline__ u16 f2bf(float x) {            // f32 -> bf16 RNE
  u32 u = __builtin_bit_cast(u32, x);
  u += 0x7fffu + ((u >> 16) & 1u);
  return (u16)(u >> 16);
}

// swizzles (ushort index space)
__device__ __forceinline__ int swzK(int r, int c)  { return r * 128 + (c ^ ((r & 7) << 3)); }
__device__ __forceinline__ int svb(int d)          { return ((d & 7) ^ ((d >> 2) & 7)) << 3; }
__device__ __forceinline__ int swzV(int d, int kv) { return d * 64 + (kv ^ svb(d)); }
__device__ __forceinline__ int swzP(int r, int c)  { return r * 64 + (c ^ ((r & 7) << 3) ^ ((r & 8) << 2)); }

__device__ __forceinline__ void gld16(const void* g, void* l) {
  __builtin_amdgcn_global_load_lds(
      (const __attribute__((address_space(1))) u32*)g,
      (__attribute__((address_space(3))) u32*)l, 16, 0, 0);
}

constexpr int Hh = 16, Ss = 2048, Dd = 128;
constexpr int QBLK = 64, KVBLK = 64;
constexpr int NT = Ss / KVBLK;            // 32 kv tiles
constexpr int TILE = KVBLK * Dd;          // 8192 elements per tile
constexpr int NELEM = 4 * Hh * Ss * Dd;   // 16777216 per tensor

// ---------------- prep: K -> bf16 pre-swizzled tiles, V -> bf16 transposed+swizzled ----------------
__global__ __launch_bounds__(256) void prep_kv(const float* __restrict__ K,
                                               const float* __restrict__ V,
                                               u16* __restrict__ Kp, u16* __restrict__ Vp) {
  __shared__ u16 Vl[KVBLK * 132];          // padded to keep uint2 alignment + spread banks
  const int blk = blockIdx.x, tid = threadIdx.x;   // blk = bh*32 + t (contiguous 64x128 tile)
  const float* kg = K + (size_t)blk * TILE;
  const float* vg = V + (size_t)blk * TILE;
  u16* kp = Kp + (size_t)blk * TILE;
  u16* vp = Vp + (size_t)blk * TILE;

  // K: output index j holds element (r = j>>7, c = (j&127)^swz) -> linear LDS fill reproduces swizzle
  #pragma unroll
  for (int it = 0; it < 4; ++it) {
    int j = (tid + it * 256) * 8;
    int r = j >> 7, c = (j & 127) ^ ((r & 7) << 3);   // bits 0-2 intact -> 8-contig run
    const float* s = kg + r * 128 + c;
    float4 a = *(const float4*)s, bq = *(const float4*)(s + 4);
    union { short8 v; u16 h[8]; } u;
    u.h[0] = f2bf(a.x);  u.h[1] = f2bf(a.y);  u.h[2] = f2bf(a.z);  u.h[3] = f2bf(a.w);
    u.h[4] = f2bf(bq.x); u.h[5] = f2bf(bq.y); u.h[6] = f2bf(bq.z); u.h[7] = f2bf(bq.w);
    *(short8*)(kp + j) = u.v;
  }
  // V: coalesced read -> LDS bf16, then transposed+swizzled coalesced write
  #pragma unroll
  for (int it = 0; it < 8; ++it) {
    int e = (tid + it * 256) * 4;
    int r = e >> 7, c = e & 127;
    float4 a = *(const float4*)(vg + e);
    uint2 w;
    w.x = (u32)f2bf(a.x) | ((u32)f2bf(a.y) << 16);
    w.y = (u32)f2bf(a.z) | ((u32)f2bf(a.w) << 16);
    *(uint2*)&Vl[r * 132 + c] = w;
  }
  __syncthreads();
  #pragma unroll
  for (int it = 0; it < 4; ++it) {
    int oj = (tid + it * 256) * 8;
    int d = oj >> 6, kv0 = (oj & 63) ^ svb(d);        // bits 0-2 intact
    union { short8 v; u16 h[8]; } u;
    #pragma unroll
    for (int i = 0; i < 8; ++i) u.h[i] = Vl[(kv0 + i) * 132 + d];
    *(short8*)(vp + oj) = u.v;
  }
}

// ---------------- main attention: bf16 K/V staged via global_load_lds, double-buffered ----------------
__global__ __launch_bounds__(256) void attn_fwd(const float* __restrict__ Q,
                                                const u16* __restrict__ Kp,
                                                const u16* __restrict__ Vp,
                                                const int* __restrict__ MSK,
                                                float* __restrict__ O) {
  __shared__ u16 Kl[2][TILE];              // 32 KB
  __shared__ u16 Vt[2][TILE];              // 32 KB
  __shared__ u16 Pl[4][16 * KVBLK];        // 8 KB
  __shared__ int sAff;

  const int tid = threadIdx.x, lane = tid & 63, wid = tid >> 6;
  const int l15 = lane & 15, lg = lane >> 4;
  // bijective XCD swizzle: 8 consecutive bh per XCD -> K/V L2-resident, qt mix balances load
  const int id = blockIdx.x;                       // 2048 blocks, 2048%8==0
  const int wg = (id & 7) * 256 + (id >> 3);
  const int bh = wg >> 5, qt = wg & 31, b = bh >> 4;
  const int qbase = qt * QBLK;

  if (tid == 0) sAff = 0;

  // Q fragments (A-layout: row = lane&15, k = (lane>>4)*8+i), scaled into exp2 domain
  const int qrowA = qbase + wid * 16 + l15;
  const float* qg = Q + ((size_t)bh * Ss + qrowA) * Dd + lg * 8;
  short8 qf[4];
  #pragma unroll
  for (int kc = 0; kc < 4; ++kc) {
    float4 x0 = *(const float4*)(qg + kc * 32);
    float4 x1 = *(const float4*)(qg + kc * 32 + 4);
    union { short8 v; u16 h[8]; } u;
    u.h[0] = f2bf(x0.x * QSCL); u.h[1] = f2bf(x0.y * QSCL);
    u.h[2] = f2bf(x0.z * QSCL); u.h[3] = f2bf(x0.w * QSCL);
    u.h[4] = f2bf(x1.x * QSCL); u.h[5] = f2bf(x1.y * QSCL);
    u.h[6] = f2bf(x1.z * QSCL); u.h[7] = f2bf(x1.w * QSCL);
    qf[kc] = u.v;
  }

  const size_t tb = (size_t)bh * NT;
  auto stage = [&](int buf, int t) {       // 8 x global_load_lds dwordx4 per thread
    const char* gk = (const char*)(Kp + (tb + t) * TILE) + wid * 4096 + lane * 16;
    const char* gv = (const char*)(Vp + (tb + t) * TILE) + wid * 4096 + lane * 16;
    char* lk = (char*)&Kl[buf][0] + wid * 4096;    // wave-uniform dest base
    char* lv = (char*)&Vt[buf][0] + wid * 4096;
    #pragma unroll
    for (int i = 0; i < 4; ++i) {
      gld16(gk + i * 1024, lk + i * 1024);
      gld16(gv + i * 1024, lv + i * 1024);
    }
  };

  float m_run[4], l_run[4];
  floatx4 oacc[8];
  const floatx4 vzero = {0.f, 0.f, 0.f, 0.f};
  #pragma unroll
  for (int r = 0; r < 4; ++r) { m_run[r] = -3.0e38f; l_run[r] = 0.0f; }
  #pragma unroll
  for (int dt = 0; dt < 8; ++dt) oacc[dt] = vzero;

  const int qi0 = qbase + wid * 16 + lg * 4;

  stage(0, 0);
  __syncthreads();

  int cur = 0;
  bool staged = true;                      // is tile t already in Kl[cur]/Vt[cur]?
  for (int t = 0; t < NT; ++t) {
    if (t > qt && !sAff) break;            // future tiles only for all-padding-masked rows
    if (!staged) { stage(cur, t); __syncthreads(); }   // rare slow path (t > qt)
    const bool pref = (t + 1 <= qt);
    if (pref) stage(cur ^ 1, t + 1);       // prefetch next tile into other buffer

    const int kvbase = t * KVBLK;
    float madd[4];
    #pragma unroll
    for (int kt = 0; kt < 4; ++kt)
      madd[kt] = MSK[b * Ss + kvbase + kt * 16 + l15] ? 0.0f : CNEG;

    // S = Q.K^T (exp2 domain)
    floatx4 sacc[4];
    #pragma unroll
    for (int kt = 0; kt < 4; ++kt) sacc[kt] = vzero;
    __builtin_amdgcn_s_setprio(1);
    #pragma unroll
    for (int kt = 0; kt < 4; ++kt) {
      const int krow = kt * 16 + l15;
      #pragma unroll
      for (int kc = 0; kc < 4; ++kc) {
        short8 kf = *(const short8*)&Kl[cur][swzK(krow, kc * 32 + lg * 8)];
        sacc[kt] = __builtin_amdgcn_mfma_f32_16x16x32_bf16(qf[kc], kf, sacc[kt], 0, 0, 0);
      }
    }
    __builtin_amdgcn_s_setprio(0);

    // masks + online softmax (C/D: row = qi0+r, col = kvbase+kt*16+l15)
    float mnew[4];
    #pragma unroll
    for (int r = 0; r < 4; ++r) mnew[r] = m_run[r];
    #pragma unroll
    for (int kt = 0; kt < 4; ++kt) {
      const int kvj = kvbase + kt * 16 + l15;
      #pragma unroll
      for (int r = 0; r < 4; ++r) {
        float s = sacc[kt][r] + madd[kt];
        if (kvj > qi0 + r) s += CNEG;
        sacc[kt][r] = s;
        mnew[r] = fmaxf(mnew[r], s);
      }
    }
    #pragma unroll
    for (int off = 1; off < 16; off <<= 1) {
      #pragma unroll
      for (int r = 0; r < 4; ++r)
        mnew[r] = fmaxf(mnew[r], __shfl_xor(mnew[r], off, 64));
    }
    float alpha[4], psum[4];
    #pragma unroll
    for (int r = 0; r < 4; ++r) {
      alpha[r] = exp2f(m_run[r] - mnew[r]);
      m_run[r] = mnew[r];
      psum[r] = 0.f;
    }
    #pragma unroll
    for (int kt = 0; kt < 4; ++kt) {
      #pragma unroll
      for (int r = 0; r < 4; ++r) {
        float p = exp2f(sacc[kt][r] - mnew[r]);
        psum[r] += p;
        Pl[wid][swzP(lg * 4 + r, kt * 16 + l15)] = f2bf(p);
      }
    }
    #pragma unroll
    for (int off = 1; off < 16; off <<= 1) {
      #pragma unroll
      for (int r = 0; r < 4; ++r)
        psum[r] += __shfl_xor(psum[r], off, 64);
    }
    #pragma unroll
    for (int r = 0; r < 4; ++r) l_run[r] = l_run[r] * alpha[r] + psum[r];
    #pragma unroll
    for (int dt = 0; dt < 8; ++dt) {
      #pragma unroll
      for (int r = 0; r < 4; ++r) oacc[dt][r] *= alpha[r];
    }

    // O += P.V
    __builtin_amdgcn_s_setprio(1);
    #pragma unroll
    for (int kc = 0; kc < 2; ++kc) {
      short8 pf = *(const short8*)&Pl[wid][swzP(l15, kc * 32 + lg * 8)];
      #pragma unroll
      for (int dt = 0; dt < 8; ++dt) {
        short8 vf = *(const short8*)&Vt[cur][swzV(dt * 16 + l15, kc * 32 + lg * 8)];
        oacc[dt] = __builtin_amdgcn_mfma_f32_16x16x32_bf16(pf, vf, oacc[dt], 0, 0, 0);
      }
    }
    __builtin_amdgcn_s_setprio(0);

    if (t == qt) {   // rows with fully-masked visible prefix need future tiles (ref quirk)
      bool aff = (m_run[0] < -7.0e8f) || (m_run[1] < -7.0e8f) ||
                 (m_run[2] < -7.0e8f) || (m_run[3] < -7.0e8f);
      if (aff) sAff = 1;                   // benign race: all writers store 1
    }
    __syncthreads();                       // publishes sAff + prefetch complete + buf reads done
    staged = pref;
    cur ^= 1;
  }

  #pragma unroll
  for (int r = 0; r < 4; ++r) {
    float inv = 1.0f / l_run[r];
    float* op = O + ((size_t)bh * Ss + qi0 + r) * Dd + l15;
    #pragma unroll
    for (int dt = 0; dt < 8; ++dt) op[dt * 16] = oacc[dt][r] * inv;
  }
}

// ---------------- fallback (round-2 self-contained kernel) if d_ws is too small ----------------
__device__ __forceinline__ int swzPf(int row, int col) { return row * 64 + (col ^ ((row & 7) << 3)); }

__global__ __launch_bounds__(256) void attn_fb(
    const float* __restrict__ Q, const float* __restrict__ K,
    const float* __restrict__ V, const int* __restrict__ MSK,
    float* __restrict__ O)
{
  __shared__ u16 Kls[KVBLK * Dd];
  __shared__ u16 Vts[Dd * KVBLK];
  __shared__ u16 Pls[4][16 * KVBLK];
  __shared__ int sAff;

  const int tid = threadIdx.x, lane = tid & 63, wid = tid >> 6;
  const int l15 = lane & 15, lg = lane >> 4;
  const int qt = blockIdx.x, bh = blockIdx.y, b = bh >> 4;
  const int qbase = qt * QBLK;
  const float scale = 0.08838834764831845f;

  const int qrowA = qbase + wid * 16 + l15;
  const float* qg = Q + ((size_t)bh * Ss + qrowA) * Dd + lg * 8;
  short8 qf[4];
  #pragma unroll
  for (int kc = 0; kc < 4; ++kc) {
    float4 x0 = *(const float4*)(qg + kc * 32);
    float4 x1 = *(const float4*)(qg + kc * 32 + 4);
    union { short8 v; u16 h[8]; } u;
    u.h[0] = f2bf(x0.x * scale); u.h[1] = f2bf(x0.y * scale);
    u.h[2] = f2bf(x0.z * scale); u.h[3] = f2bf(x0.w * scale);
    u.h[4] = f2bf(x1.x * scale); u.h[5] = f2bf(x1.y * scale);
    u.h[6] = f2bf(x1.z * scale); u.h[7] = f2bf(x1.w * scale);
    qf[kc] = u.v;
  }

  float m_run[4], l_run[4];
  floatx4 oacc[8];
  const floatx4 vzero = {0.f, 0.f, 0.f, 0.f};
  #pragma unroll
  for (int r = 0; r < 4; ++r) { m_run[r] = -3.0e38f; l_run[r] = 0.0f; }
  #pragma unroll
  for (int dt = 0; dt < 8; ++dt) oacc[dt] = vzero;
  const int qi0 = qbase + wid * 16 + lg * 4;

  for (int t = 0; t < NT; ++t) {
    if (t > qt && !sAff) break;
    const int kvbase = t * KVBLK;
    const float* kg = K + ((size_t)bh * Ss + kvbase) * Dd;
    const float* vg = V + ((size_t)bh * Ss + kvbase) * Dd;
    #pragma unroll
    for (int it = 0; it < 8; ++it) {
      int e = (tid + it * 256) * 4;
      int r0 = e >> 7, c0 = e & 127;
      float4 x = *(const float4*)(kg + e);
      uint2 hk;
      hk.x = (u32)f2bf(x.x) | ((u32)f2bf(x.y) << 16);
      hk.y = (u32)f2bf(x.z) | ((u32)f2bf(x.w) << 16);
      *(uint2*)&Kls[swzK(r0, c0)] = hk;
      float4 y = *(const float4*)(vg + e);
      u16 hv[4] = { f2bf(y.x), f2bf(y.y), f2bf(y.z), f2bf(y.w) };
      #pragma unroll
      for (int j = 0; j < 4; ++j) Vts[swzV(c0 + j, r0)] = hv[j];
    }
    __syncthreads();

    float madd[4];
    #pragma unroll
    for (int kt = 0; kt < 4; ++kt)
      madd[kt] = MSK[b * Ss + kvbase + kt * 16 + l15] ? 0.0f : NEGF;

    floatx4 sacc[4];
    #pragma unroll
    for (int kt = 0; kt < 4; ++kt) sacc[kt] = vzero;
    #pragma unroll
    for (int kt = 0; kt < 4; ++kt) {
      const int krow = kt * 16 + l15;
      #pragma unroll
      for (int kc = 0; kc < 4; ++kc) {
        short8 kf = *(const short8*)&Kls[swzK(krow, kc * 32 + lg * 8)];
        sacc[kt] = __builtin_amdgcn_mfma_f32_16x16x32_bf16(qf[kc], kf, sacc[kt], 0, 0, 0);
      }
    }

    float mnew[4];
    #pragma unroll
    for (int r = 0; r < 4; ++r) mnew[r] = m_run[r];
    #pragma unroll
    for (int kt = 0; kt < 4; ++kt) {
      const int kvj = kvbase + kt * 16 + l15;
      #pragma unroll
      for (int r = 0; r < 4; ++r) {
        float s = sacc[kt][r] + madd[kt];
        if (kvj > qi0 + r) s += NEGF;
        sacc[kt][r] = s;
        mnew[r] = fmaxf(mnew[r], s);
      }
    }
    #pragma unroll
    for (int off = 1; off < 16; off <<= 1) {
      #pragma unroll
      for (int r = 0; r < 4; ++r)
        mnew[r] = fmaxf(mnew[r], __shfl_xor(mnew[r], off, 64));
    }
    float alpha[4], psum[4];
    #pragma unroll
    for (int r = 0; r < 4; ++r) {
      alpha[r] = __expf(m_run[r] - mnew[r]);
      m_run[r] = mnew[r];
      psum[r] = 0.f;
    }
    #pragma unroll
    for (int kt = 0; kt < 4; ++kt) {
      #pragma unroll
      for (int r = 0; r < 4; ++r) {
        float p = __expf(sacc[kt][r] - mnew[r]);
        psum[r] += p;
        Pls[wid][swzPf(lg * 4 + r, kt * 16 + l15)] = f2bf(p);
      }
    }
    #pragma unroll
    for (int off = 1; off < 16; off <<= 1) {
      #pragma unroll
      for (int r = 0; r < 4; ++r)
        psum[r] += __shfl_xor(psum[r], off, 64);
    }
    #pragma unroll
    for (int r = 0; r < 4; ++r) l_run[r] = l_run[r] * alpha[r] + psum[r];
    #pragma unroll
    for (int dt = 0; dt < 8; ++dt) {
      #pragma unroll
      for (int r = 0; r < 4; ++r) oacc[dt][r] *= alpha[r];
    }
    #pragma unroll
    for (int kc = 0; kc < 2; ++kc) {
      short8 pf = *(const short8*)&Pls[wid][swzPf(l15, kc * 32 + lg * 8)];
      #pragma unroll
      for (int dt = 0; dt < 8; ++dt) {
        short8 vf = *(const short8*)&Vts[swzV(dt * 16 + l15, kc * 32 + lg * 8)];
        oacc[dt] = __builtin_amdgcn_mfma_f32_16x16x32_bf16(pf, vf, oacc[dt], 0, 0, 0);
      }
    }
    __syncthreads();

    if (t == qt) {
      if (tid == 0) sAff = 0;
      __syncthreads();
      bool aff = (m_run[0] < -5.0e8f) || (m_run[1] < -5.0e8f) ||
                 (m_run[2] < -5.0e8f) || (m_run[3] < -5.0e8f);
      if (aff) sAff = 1;
      __syncthreads();
    }
  }

  #pragma unroll
  for (int r = 0; r < 4; ++r) {
    float inv = 1.0f / l_run[r];
    float* op = O + ((size_t)bh * Ss + qi0 + r) * Dd + l15;
    #pragma unroll
    for (int dt = 0; dt < 8; ++dt) op[dt * 16] = oacc[dt][r] * inv;
  }
}

extern "C" void kernel_launch(void* const* d_in, const int* in_sizes, int n_in,
                              void* d_out, int out_size, void* d_ws, size_t ws_size,
                              hipStream_t stream) {
  const float* q = (const float*)d_in[0];
  const float* k = (const float*)d_in[1];
  const float* v = (const float*)d_in[2];
  const int* mask = (const int*)d_in[3];
  float* out = (float*)d_out;

  const size_t need = (size_t)2 * NELEM * sizeof(u16);   // 67.1 MB for Kp + Vp
  if (ws_size >= need) {
    u16* Kp = (u16*)d_ws;
    u16* Vp = Kp + NELEM;
    prep_kv<<<dim3(64 * NT), 256, 0, stream>>>(k, v, Kp, Vp);
    attn_fwd<<<dim3(2048), 256, 0, stream>>>(q, Kp, Vp, mask, out);
  } else {
    attn_fb<<<dim3(NT, 64), 256, 0, stream>>>(q, k, v, mask, out);
  }
}

// Round 4
// 270.401 us; speedup vs baseline: 1.7154x; 1.1714x over previous
//
#include <hip/hip_runtime.h>

typedef unsigned short u16;
typedef unsigned int   u32;
typedef __attribute__((ext_vector_type(8))) short  short8;   // 8 x bf16
typedef __attribute__((ext_vector_type(4))) float  floatx4;

#define CNEG  (-1.4426950408889634e9f)   // -1e9 * log2(e)  (exp2 domain)
#define QSCL  (0.12753129020334545f)     // (1/sqrt(128)) * log2(e)
#define NEGF  (-1000000000.0f)           // fallback kernel (exp domain)
#define DEFER_THR 8.0f

__device__ __forceinline__ u16 f2bf(float x) {            // f32 -> bf16 RNE
  u32 u = __builtin_bit_cast(u32, x);
  u += 0x7fffu + ((u >> 16) & 1u);
  return (u16)(u >> 16);
}
__device__ __forceinline__ u32 cvtpk(float lo, float hi) { // 2xf32 -> packed bf16
  u32 r;
  asm("v_cvt_pk_bf16_f32 %0, %1, %2" : "=v"(r) : "v"(lo), "v"(hi));
  return r;
}

// swizzles (ushort index space)
__device__ __forceinline__ int swzK(int r, int c)  { return r * 128 + (c ^ ((r & 7) << 3)); }
__device__ __forceinline__ int svb(int d)          { return ((d & 7) ^ ((d >> 2) & 7)) << 3; }
__device__ __forceinline__ int swzV(int d, int kv) { return d * 64 + (kv ^ svb(d)); }

__device__ __forceinline__ void gld16(const void* g, void* l) {
  __builtin_amdgcn_global_load_lds(
      (const __attribute__((address_space(1))) u32*)g,
      (__attribute__((address_space(3))) u32*)l, 16, 0, 0);
}

constexpr int Hh = 16, Ss = 2048, Dd = 128;
constexpr int QBLK = 64, KVBLK = 64;
constexpr int NT = Ss / KVBLK;            // 32 kv tiles
constexpr int TILE = KVBLK * Dd;          // 8192 elements per tile
constexpr int NELEM = 4 * Hh * Ss * Dd;   // 16777216 per tensor
constexpr int MASKN = 4 * Ss;             // 8192 mask entries

// ---------------- prep: K/V -> bf16 pre-swizzled; mask -> float CNEG-adds ----------------
__global__ __launch_bounds__(256) void prep_kv(const float* __restrict__ K,
                                               const float* __restrict__ V,
                                               const int* __restrict__ MSK,
                                               u16* __restrict__ Kp, u16* __restrict__ Vp,
                                               float* __restrict__ Mg) {
  __shared__ u16 Vl[KVBLK * 132];
  const int blk = blockIdx.x, tid = threadIdx.x;   // blk = bh*32 + t
  const float* kg = K + (size_t)blk * TILE;
  const float* vg = V + (size_t)blk * TILE;
  u16* kp = Kp + (size_t)blk * TILE;
  u16* vp = Vp + (size_t)blk * TILE;

  if (blk < MASKN / 256) {                         // mask -> exp2-domain additive floats
    int i = blk * 256 + tid;
    Mg[i] = MSK[i] ? 0.0f : CNEG;
  }

  // K: output index j holds element (r = j>>7, c = (j&127)^swz)
  #pragma unroll
  for (int it = 0; it < 4; ++it) {
    int j = (tid + it * 256) * 8;
    int r = j >> 7, c = (j & 127) ^ ((r & 7) << 3);
    const float* s = kg + r * 128 + c;
    float4 a = *(const float4*)s, bq = *(const float4*)(s + 4);
    union { short8 v; u16 h[8]; } u;
    u.h[0] = f2bf(a.x);  u.h[1] = f2bf(a.y);  u.h[2] = f2bf(a.z);  u.h[3] = f2bf(a.w);
    u.h[4] = f2bf(bq.x); u.h[5] = f2bf(bq.y); u.h[6] = f2bf(bq.z); u.h[7] = f2bf(bq.w);
    *(short8*)(kp + j) = u.v;
  }
  // V: coalesced read -> LDS bf16, then transposed+swizzled write
  #pragma unroll
  for (int it = 0; it < 8; ++it) {
    int e = (tid + it * 256) * 4;
    int r = e >> 7, c = e & 127;
    float4 a = *(const float4*)(vg + e);
    uint2 w;
    w.x = (u32)f2bf(a.x) | ((u32)f2bf(a.y) << 16);
    w.y = (u32)f2bf(a.z) | ((u32)f2bf(a.w) << 16);
    *(uint2*)&Vl[r * 132 + c] = w;
  }
  __syncthreads();
  #pragma unroll
  for (int it = 0; it < 4; ++it) {
    int oj = (tid + it * 256) * 8;
    int d = oj >> 6, kv0 = (oj & 63) ^ svb(d);
    union { short8 v; u16 h[8]; } u;
    #pragma unroll
    for (int i = 0; i < 8; ++i) u.h[i] = Vl[(kv0 + i) * 132 + d];
    *(short8*)(vp + oj) = u.v;
  }
}

// ---------------- main: swapped-operand MFMA, fully in-register softmax ----------------
__global__ __launch_bounds__(256) void attn_fwd(const float* __restrict__ Q,
                                                const u16* __restrict__ Kp,
                                                const u16* __restrict__ Vp,
                                                const float* __restrict__ Mg,
                                                float* __restrict__ O) {
  __shared__ u16 Kl[2][TILE];              // 32 KB
  __shared__ u16 Vt[2][TILE];              // 32 KB
  __shared__ int sAff;

  const int tid = threadIdx.x, lane = tid & 63, wid = tid >> 6;
  const int l15 = lane & 15, lg = lane >> 4;
  const int id = blockIdx.x;                       // bijective XCD swizzle (2048 % 8 == 0)
  const int wg = (id & 7) * 256 + (id >> 3);
  const int bh = wg >> 5, qt = wg & 31, b = bh >> 4;
  const int qbase = qt * QBLK;
  const int qi = qbase + wid * 16 + l15;           // this lane's single q-row

  if (tid == 0) sAff = 0;

  // Q fragments (used as B operand; layout identical to A): col=q=l15, k=lg*8+i
  const float* qg = Q + ((size_t)bh * Ss + qi) * Dd + lg * 8;
  short8 qf[4];
  #pragma unroll
  for (int kc = 0; kc < 4; ++kc) {
    float4 x0 = *(const float4*)(qg + kc * 32);
    float4 x1 = *(const float4*)(qg + kc * 32 + 4);
    union { short8 v; u16 h[8]; } u;
    u.h[0] = f2bf(x0.x * QSCL); u.h[1] = f2bf(x0.y * QSCL);
    u.h[2] = f2bf(x0.z * QSCL); u.h[3] = f2bf(x0.w * QSCL);
    u.h[4] = f2bf(x1.x * QSCL); u.h[5] = f2bf(x1.y * QSCL);
    u.h[6] = f2bf(x1.z * QSCL); u.h[7] = f2bf(x1.w * QSCL);
    qf[kc] = u.v;
  }

  const size_t tb = (size_t)bh * NT;
  auto stage = [&](int buf, int t) {
    const char* gk = (const char*)(Kp + (tb + t) * TILE) + wid * 4096 + lane * 16;
    const char* gv = (const char*)(Vp + (tb + t) * TILE) + wid * 4096 + lane * 16;
    char* lk = (char*)&Kl[buf][0] + wid * 4096;
    char* lv = (char*)&Vt[buf][0] + wid * 4096;
    #pragma unroll
    for (int i = 0; i < 4; ++i) {
      gld16(gk + i * 1024, lk + i * 1024);
      gld16(gv + i * 1024, lv + i * 1024);
    }
  };

  float m_run = -3.0e38f, l_run = 0.0f;
  floatx4 oacc[8];
  const floatx4 vzero = {0.f, 0.f, 0.f, 0.f};
  #pragma unroll
  for (int dt = 0; dt < 8; ++dt) oacc[dt] = vzero;

  // bpermute byte-indices for P redistribution (computed once)
  const int idxA = (l15 + 16 * ((2 * lg) & 3)) * 4;
  const int idxB = (l15 + 16 * ((2 * lg + 1) & 3)) * 4;

  stage(0, 0);
  __syncthreads();

  int cur = 0;
  bool staged = true;
  for (int t = 0; t < NT; ++t) {
    if (t > qt && !sAff) break;            // future tiles only for the padding-quirk rows
    if (!staged) { stage(cur, t); __syncthreads(); }
    const bool pref = (t + 1 <= qt);
    if (pref) stage(cur ^ 1, t + 1);

    const int kvbase = t * KVBLK;
    float4 md[4];                          // additive mask values for this lane's 16 kv's
    #pragma unroll
    for (int kt = 0; kt < 4; ++kt)
      md[kt] = *(const float4*)(Mg + b * Ss + kvbase + kt * 16 + lg * 4);

    // S^T = K . Q^T  (D[kv][q]; this lane: q=l15, kv = kvbase + kt*16 + lg*4 + r)
    floatx4 sacc[4];
    #pragma unroll
    for (int kt = 0; kt < 4; ++kt) sacc[kt] = vzero;
    __builtin_amdgcn_s_setprio(1);
    #pragma unroll
    for (int kt = 0; kt < 4; ++kt) {
      const int krow = kt * 16 + l15;
      #pragma unroll
      for (int kc = 0; kc < 4; ++kc) {
        short8 kf = *(const short8*)&Kl[cur][swzK(krow, kc * 32 + lg * 8)];
        sacc[kt] = __builtin_amdgcn_mfma_f32_16x16x32_bf16(kf, qf[kc], sacc[kt], 0, 0, 0);
      }
    }
    __builtin_amdgcn_s_setprio(0);

    // scores + masks (additive in f32, matching reference rounding)
    float p[4][4];
    #pragma unroll
    for (int kt = 0; kt < 4; ++kt) {
      p[kt][0] = sacc[kt][0] + md[kt].x;
      p[kt][1] = sacc[kt][1] + md[kt].y;
      p[kt][2] = sacc[kt][2] + md[kt].z;
      p[kt][3] = sacc[kt][3] + md[kt].w;
    }
    if (t == qt) {                         // causal only on the diagonal tile
      #pragma unroll
      for (int kt = 0; kt < 4; ++kt)
        #pragma unroll
        for (int r = 0; r < 4; ++r)
          if (kvbase + kt * 16 + lg * 4 + r > qi) p[kt][r] += CNEG;
    } else if (t > qt) {                   // quirk tiles: every col is future
      #pragma unroll
      for (int kt = 0; kt < 4; ++kt)
        #pragma unroll
        for (int r = 0; r < 4; ++r) p[kt][r] += CNEG;
    }

    // row max (per-thread tree + 2 shuffles across lg groups)
    float pmax = p[0][0];
    #pragma unroll
    for (int kt = 0; kt < 4; ++kt)
      #pragma unroll
      for (int r = 0; r < 4; ++r) pmax = fmaxf(pmax, p[kt][r]);
    pmax = fmaxf(pmax, __shfl_xor(pmax, 16, 64));
    pmax = fmaxf(pmax, __shfl_xor(pmax, 32, 64));

    // defer-max: skip O-rescale when max growth bounded (exp2 values <= 2^8)
    const bool skip = __all(pmax <= m_run + DEFER_THR);
    float mn = m_run;
    if (!skip) {
      mn = fmaxf(m_run, pmax);
      const float alpha = exp2f(m_run - mn);
      m_run = mn;
      l_run *= alpha;
      #pragma unroll
      for (int dt = 0; dt < 8; ++dt)
        #pragma unroll
        for (int r = 0; r < 4; ++r) oacc[dt][r] *= alpha;
    }

    float ps = 0.0f;
    #pragma unroll
    for (int kt = 0; kt < 4; ++kt)
      #pragma unroll
      for (int r = 0; r < 4; ++r) {
        const float pv = exp2f(p[kt][r] - mn);
        p[kt][r] = pv;
        ps += pv;
      }
    ps += __shfl_xor(ps, 16, 64);
    ps += __shfl_xor(ps, 32, 64);
    l_run += ps;

    // pack P to bf16 pairs, redistribute quads to B-fragment layout
    u32 pkw[4][2];
    #pragma unroll
    for (int kt = 0; kt < 4; ++kt) {
      pkw[kt][0] = cvtpk(p[kt][0], p[kt][1]);
      pkw[kt][1] = cvtpk(p[kt][2], p[kt][3]);
    }
    union { short8 v; u32 w[4]; } pf[2];
    #pragma unroll
    for (int kc = 0; kc < 2; ++kc) {
      #pragma unroll
      for (int wq = 0; wq < 4; ++wq) {
        const int ws = wq & 1;
        const int idx = (wq >> 1) ? idxB : idxA;
        const u32 a  = (u32)__builtin_amdgcn_ds_bpermute(idx, (int)pkw[2 * kc][ws]);
        const u32 bb = (u32)__builtin_amdgcn_ds_bpermute(idx, (int)pkw[2 * kc + 1][ws]);
        pf[kc].w[wq] = (lg & 2) ? bb : a;
      }
    }

    // O^T += V^T . P^T  (D[d][q]; this lane: q=l15, d = dt*16 + lg*4 + r)
    __builtin_amdgcn_s_setprio(1);
    #pragma unroll
    for (int kc = 0; kc < 2; ++kc) {
      #pragma unroll
      for (int dt = 0; dt < 8; ++dt) {
        short8 vf = *(const short8*)&Vt[cur][swzV(dt * 16 + l15, kc * 32 + lg * 8)];
        oacc[dt] = __builtin_amdgcn_mfma_f32_16x16x32_bf16(vf, pf[kc].v, oacc[dt], 0, 0, 0);
      }
    }
    __builtin_amdgcn_s_setprio(0);

    if (t == qt) {
      if (m_run < -1.0e9f) sAff = 1;       // fully-masked visible prefix (benign race)
    }
    __syncthreads();
    staged = pref;
    cur ^= 1;
  }

  // epilogue: O[qi][d] = oacc/l, d = dt*16 + lg*4 + r  -> float4 stores
  const float inv = 1.0f / l_run;
  float* orow = O + ((size_t)bh * Ss + qi) * Dd;
  #pragma unroll
  for (int dt = 0; dt < 8; ++dt) {
    float4 o4;
    o4.x = oacc[dt][0] * inv; o4.y = oacc[dt][1] * inv;
    o4.z = oacc[dt][2] * inv; o4.w = oacc[dt][3] * inv;
    *(float4*)(orow + dt * 16 + lg * 4) = o4;
  }
}

// ---------------- fallback (round-2 self-contained kernel) if d_ws is too small ----------------
__device__ __forceinline__ int swzPf(int row, int col) { return row * 64 + (col ^ ((row & 7) << 3)); }

__global__ __launch_bounds__(256) void attn_fb(
    const float* __restrict__ Q, const float* __restrict__ K,
    const float* __restrict__ V, const int* __restrict__ MSK,
    float* __restrict__ O)
{
  __shared__ u16 Kls[KVBLK * Dd];
  __shared__ u16 Vts[Dd * KVBLK];
  __shared__ u16 Pls[4][16 * KVBLK];
  __shared__ int sAff;

  const int tid = threadIdx.x, lane = tid & 63, wid = tid >> 6;
  const int l15 = lane & 15, lg = lane >> 4;
  const int qt = blockIdx.x, bh = blockIdx.y, b = bh >> 4;
  const int qbase = qt * QBLK;
  const float scale = 0.08838834764831845f;

  const int qrowA = qbase + wid * 16 + l15;
  const float* qg = Q + ((size_t)bh * Ss + qrowA) * Dd + lg * 8;
  short8 qf[4];
  #pragma unroll
  for (int kc = 0; kc < 4; ++kc) {
    float4 x0 = *(const float4*)(qg + kc * 32);
    float4 x1 = *(const float4*)(qg + kc * 32 + 4);
    union { short8 v; u16 h[8]; } u;
    u.h[0] = f2bf(x0.x * scale); u.h[1] = f2bf(x0.y * scale);
    u.h[2] = f2bf(x0.z * scale); u.h[3] = f2bf(x0.w * scale);
    u.h[4] = f2bf(x1.x * scale); u.h[5] = f2bf(x1.y * scale);
    u.h[6] = f2bf(x1.z * scale); u.h[7] = f2bf(x1.w * scale);
    qf[kc] = u.v;
  }

  float m_run[4], l_run[4];
  floatx4 oacc[8];
  const floatx4 vzero = {0.f, 0.f, 0.f, 0.f};
  #pragma unroll
  for (int r = 0; r < 4; ++r) { m_run[r] = -3.0e38f; l_run[r] = 0.0f; }
  #pragma unroll
  for (int dt = 0; dt < 8; ++dt) oacc[dt] = vzero;
  const int qi0 = qbase + wid * 16 + lg * 4;

  for (int t = 0; t < NT; ++t) {
    if (t > qt && !sAff) break;
    const int kvbase = t * KVBLK;
    const float* kg = K + ((size_t)bh * Ss + kvbase) * Dd;
    const float* vg = V + ((size_t)bh * Ss + kvbase) * Dd;
    #pragma unroll
    for (int it = 0; it < 8; ++it) {
      int e = (tid + it * 256) * 4;
      int r0 = e >> 7, c0 = e & 127;
      float4 x = *(const float4*)(kg + e);
      uint2 hk;
      hk.x = (u32)f2bf(x.x) | ((u32)f2bf(x.y) << 16);
      hk.y = (u32)f2bf(x.z) | ((u32)f2bf(x.w) << 16);
      *(uint2*)&Kls[swzK(r0, c0)] = hk;
      float4 y = *(const float4*)(vg + e);
      u16 hv[4] = { f2bf(y.x), f2bf(y.y), f2bf(y.z), f2bf(y.w) };
      #pragma unroll
      for (int j = 0; j < 4; ++j) Vts[swzV(c0 + j, r0)] = hv[j];
    }
    __syncthreads();

    float madd[4];
    #pragma unroll
    for (int kt = 0; kt < 4; ++kt)
      madd[kt] = MSK[b * Ss + kvbase + kt * 16 + l15] ? 0.0f : NEGF;

    floatx4 sacc[4];
    #pragma unroll
    for (int kt = 0; kt < 4; ++kt) sacc[kt] = vzero;
    #pragma unroll
    for (int kt = 0; kt < 4; ++kt) {
      const int krow = kt * 16 + l15;
      #pragma unroll
      for (int kc = 0; kc < 4; ++kc) {
        short8 kf = *(const short8*)&Kls[swzK(krow, kc * 32 + lg * 8)];
        sacc[kt] = __builtin_amdgcn_mfma_f32_16x16x32_bf16(qf[kc], kf, sacc[kt], 0, 0, 0);
      }
    }

    float mnew[4];
    #pragma unroll
    for (int r = 0; r < 4; ++r) mnew[r] = m_run[r];
    #pragma unroll
    for (int kt = 0; kt < 4; ++kt) {
      const int kvj = kvbase + kt * 16 + l15;
      #pragma unroll
      for (int r = 0; r < 4; ++r) {
        float s = sacc[kt][r] + madd[kt];
        if (kvj > qi0 + r) s += NEGF;
        sacc[kt][r] = s;
        mnew[r] = fmaxf(mnew[r], s);
      }
    }
    #pragma unroll
    for (int off = 1; off < 16; off <<= 1) {
      #pragma unroll
      for (int r = 0; r < 4; ++r)
        mnew[r] = fmaxf(mnew[r], __shfl_xor(mnew[r], off, 64));
    }
    float alpha[4], psum[4];
    #pragma unroll
    for (int r = 0; r < 4; ++r) {
      alpha[r] = __expf(m_run[r] - mnew[r]);
      m_run[r] = mnew[r];
      psum[r] = 0.f;
    }
    #pragma unroll
    for (int kt = 0; kt < 4; ++kt) {
      #pragma unroll
      for (int r = 0; r < 4; ++r) {
        float p = __expf(sacc[kt][r] - mnew[r]);
        psum[r] += p;
        Pls[wid][swzPf(lg * 4 + r, kt * 16 + l15)] = f2bf(p);
      }
    }
    #pragma unroll
    for (int off = 1; off < 16; off <<= 1) {
      #pragma unroll
      for (int r = 0; r < 4; ++r)
        psum[r] += __shfl_xor(psum[r], off, 64);
    }
    #pragma unroll
    for (int r = 0; r < 4; ++r) l_run[r] = l_run[r] * alpha[r] + psum[r];
    #pragma unroll
    for (int dt = 0; dt < 8; ++dt) {
      #pragma unroll
      for (int r = 0; r < 4; ++r) oacc[dt][r] *= alpha[r];
    }
    #pragma unroll
    for (int kc = 0; kc < 2; ++kc) {
      short8 pfr = *(const short8*)&Pls[wid][swzPf(l15, kc * 32 + lg * 8)];
      #pragma unroll
      for (int dt = 0; dt < 8; ++dt) {
        short8 vf = *(const short8*)&Vts[swzV(dt * 16 + l15, kc * 32 + lg * 8)];
        oacc[dt] = __builtin_amdgcn_mfma_f32_16x16x32_bf16(pfr, vf, oacc[dt], 0, 0, 0);
      }
    }
    __syncthreads();

    if (t == qt) {
      if (tid == 0) sAff = 0;
      __syncthreads();
      bool aff = (m_run[0] < -5.0e8f) || (m_run[1] < -5.0e8f) ||
                 (m_run[2] < -5.0e8f) || (m_run[3] < -5.0e8f);
      if (aff) sAff = 1;
      __syncthreads();
    }
  }

  #pragma unroll
  for (int r = 0; r < 4; ++r) {
    float inv = 1.0f / l_run[r];
    float* op = O + ((size_t)bh * Ss + qi0 + r) * Dd + l15;
    #pragma unroll
    for (int dt = 0; dt < 8; ++dt) op[dt * 16] = oacc[dt][r] * inv;
  }
}

extern "C" void kernel_launch(void* const* d_in, const int* in_sizes, int n_in,
                              void* d_out, int out_size, void* d_ws, size_t ws_size,
                              hipStream_t stream) {
  const float* q = (const float*)d_in[0];
  const float* k = (const float*)d_in[1];
  const float* v = (const float*)d_in[2];
  const int* mask = (const int*)d_in[3];
  float* out = (float*)d_out;

  const size_t need = (size_t)2 * NELEM * sizeof(u16) + (size_t)MASKN * sizeof(float);
  if (ws_size >= need) {
    u16* Kp = (u16*)d_ws;
    u16* Vp = Kp + NELEM;
    float* Mg = (float*)(Vp + NELEM);
    prep_kv<<<dim3(64 * NT), 256, 0, stream>>>(k, v, mask, Kp, Vp, Mg);
    attn_fwd<<<dim3(2048), 256, 0, stream>>>(q, Kp, Vp, Mg, out);
  } else {
    attn_fb<<<dim3(NT, 64), 256, 0, stream>>>(q, k, v, mask, out);
  }
}